// Round 1
// baseline (524.255 us; speedup 1.0000x reference)
//
#include <hip/hip_runtime.h>
#include <hip/hip_bf16.h>
#include <stdint.h>

#define G_ 8
#define T_ 1024
#define K_ 7168
#define N_ 2048
#define KB_ (K_/128)   // 56 quant blocks along K
#define NB_ (N_/128)   // 16 quant blocks along N

typedef __attribute__((ext_vector_type(4))) float f32x4;
typedef __attribute__((ext_vector_type(2))) float f32x2;
typedef __attribute__((ext_vector_type(8))) short bf16x8;

// ---------------------------------------------------------------------------
// Kernel 1: activation quantize->dequantize (fp8 e4m3, per (token,128-block)
// amax/448 scale), output bf16 into workspace. One 32-lane group per block:
// 32 lanes x float4 = 128 elements.
// ---------------------------------------------------------------------------
__global__ __launch_bounds__(256) void act_quant_kernel(
    const float* __restrict__ xs, __hip_bfloat16* __restrict__ xq)
{
    const int grp = (blockIdx.x * 256 + threadIdx.x) >> 5;   // quant-block id
    const int l   = threadIdx.x & 31;
    const size_t base = (size_t)grp * 128 + (size_t)l * 4;

    const float4 v = *(const float4*)(xs + base);
    float am = fmaxf(fmaxf(fabsf(v.x), fabsf(v.y)), fmaxf(fabsf(v.z), fabsf(v.w)));
#pragma unroll
    for (int off = 1; off <= 16; off <<= 1)
        am = fmaxf(am, __shfl_xor(am, off, 64));
    const float s = am / 448.0f;

    // quantize (precise div like the reference) -> fp8 e4m3 (HW RNE) -> back
    const int pk01 = __builtin_amdgcn_cvt_pk_fp8_f32(v.x / s, v.y / s, 0, false);
    const int pk23 = __builtin_amdgcn_cvt_pk_fp8_f32(v.z / s, v.w / s, 0, false);
    const f32x2 d01 = __builtin_amdgcn_cvt_pk_f32_fp8(pk01, false);
    const f32x2 d23 = __builtin_amdgcn_cvt_pk_f32_fp8(pk23, false);

    union { uint2 u; __hip_bfloat16 h[4]; } p;
    p.h[0] = __float2bfloat16(d01[0] * s);
    p.h[1] = __float2bfloat16(d01[1] * s);
    p.h[2] = __float2bfloat16(d23[0] * s);
    p.h[3] = __float2bfloat16(d23[1] * s);
    *(uint2*)(xq + base) = p.u;
}

// ---------------------------------------------------------------------------
// Kernel 2: grouped bf16 GEMM with fused weight dequant.
//   A = xq[g]  [T][K] bf16 (staged via global_load_lds, width 16)
//   B^T = weight[g] [N][K] fp8-codes-in-fp32 (reg-staged: *scale -> bf16 -> LDS)
//   tile 128x128, BK=64, 4 waves, each wave 64x64 (4x4 frags of 16x16x32)
// ---------------------------------------------------------------------------
typedef __attribute__((address_space(3))) uint32_t lds_u32_t;
typedef const __attribute__((address_space(1))) uint32_t gbl_u32_t;

__device__ __forceinline__ void gload_lds16(const void* gsrc, void* lds_wave_base)
{
    __builtin_amdgcn_global_load_lds(
        (gbl_u32_t*)(uintptr_t)gsrc,
        (lds_u32_t*)(uint32_t)(uintptr_t)lds_wave_base,
        16, 0, 0);
}

__global__ __launch_bounds__(256) void gemm_kernel(
    const __hip_bfloat16* __restrict__ xq, const float* __restrict__ w,
    const float* __restrict__ scale, const float* __restrict__ bias,
    float* __restrict__ y)
{
    __shared__ __hip_bfloat16 As[128][64];   // 16 KB
    __shared__ __hip_bfloat16 Bs[128][64];   // 16 KB

    const int bx = blockIdx.x;
    const int g  = bx >> 7;          // 128 tiles per group
    const int tm = (bx >> 4) & 7;    // T/128 = 8
    const int tn = bx & 15;          // N/128 = 16
    const int t0 = tm * 128;
    const int n0 = tn * 128;

    const int tid  = threadIdx.x;
    const int lane = tid & 63;
    const int wid  = tid >> 6;

    const __hip_bfloat16* Ag = xq + (size_t)g * T_ * K_;
    const float*          Wg = w  + (size_t)g * N_ * K_;

    // A staging map: call j covers rows [j*32, j*32+32); within a wave:
    // row = j*32 + wid*8 + (lane>>3), col elems = (lane&7)*8. LDS linear.
    const int arow = tid >> 3;         // j=0 row
    const int acol = (tid & 7) * 8;    // element col within BK

    // B staging map: iter i: flat = i*1024 + tid*4 -> r = flat/64, c = flat%64
    const int brow0 = tid >> 4;        // r for i=0
    const int bcol  = (tid & 15) * 4;

    const int wr  = (wid >> 1) * 64;   // wave row origin in tile
    const int wc  = (wid & 1) * 64;    // wave col origin in tile
    const int l15 = lane & 15;
    const int lhi = lane >> 4;

    f32x4 acc[4][4] = {};

    for (int kt = 0; kt < K_ / 64; ++kt) {
        const int k0 = kt * 64;

        // ---- stage A: async global bf16 -> LDS (4 x 16B per thread-wave) ----
#pragma unroll
        for (int j = 0; j < 4; ++j) {
            const __hip_bfloat16* src =
                Ag + (size_t)(t0 + j * 32 + arow) * K_ + k0 + acol;
            void* dst = (char*)(&As[0][0]) + j * 4096 + wid * 1024;
            gload_lds16(src, dst);
        }

        // ---- stage B: fp32 codes * block scale -> bf16 -> LDS ----
        const float svw = scale[((size_t)g * NB_ + tn) * KB_ + (kt >> 1)];
#pragma unroll
        for (int i = 0; i < 8; ++i) {
            const int r = i * 16 + brow0;
            const float4 wv = *(const float4*)(Wg + (size_t)(n0 + r) * K_ + k0 + bcol);
            union { uint2 u; __hip_bfloat16 h[4]; } p;
            p.h[0] = __float2bfloat16(wv.x * svw);
            p.h[1] = __float2bfloat16(wv.y * svw);
            p.h[2] = __float2bfloat16(wv.z * svw);
            p.h[3] = __float2bfloat16(wv.w * svw);
            *(uint2*)(&Bs[r][bcol]) = p.u;
        }

        __syncthreads();   // drains vmcnt (global_load_lds) + lgkm (ds_write)

        // ---- compute: 2 k-slices of 32, 4x4 MFMA each ----
#pragma unroll
        for (int kk = 0; kk < 64; kk += 32) {
            bf16x8 av[4], bv[4];
#pragma unroll
            for (int m = 0; m < 4; ++m)
                av[m] = *(const bf16x8*)&As[wr + m * 16 + l15][kk + lhi * 8];
#pragma unroll
            for (int n = 0; n < 4; ++n)
                bv[n] = *(const bf16x8*)&Bs[wc + n * 16 + l15][kk + lhi * 8];
#pragma unroll
            for (int m = 0; m < 4; ++m)
#pragma unroll
                for (int n = 0; n < 4; ++n)
                    acc[m][n] = __builtin_amdgcn_mfma_f32_16x16x32_bf16(
                        av[m], bv[n], acc[m][n], 0, 0, 0);
        }

        __syncthreads();
    }

    // ---- epilogue: C/D layout col = lane&15, row = (lane>>4)*4 + j ----
    float* Yg = y + (size_t)g * T_ * N_;
#pragma unroll
    for (int n = 0; n < 4; ++n) {
        const int col = n0 + wc + n * 16 + l15;
        const float bv = bias[g * N_ + col];
#pragma unroll
        for (int m = 0; m < 4; ++m) {
            const int row0 = t0 + wr + m * 16 + lhi * 4;
#pragma unroll
            for (int j = 0; j < 4; ++j)
                Yg[(size_t)(row0 + j) * N_ + col] = acc[m][n][j] + bv;
        }
    }
}

// ---------------------------------------------------------------------------
extern "C" void kernel_launch(void* const* d_in, const int* in_sizes, int n_in,
                              void* d_out, int out_size, void* d_ws, size_t ws_size,
                              hipStream_t stream)
{
    const float* xs     = (const float*)d_in[0];
    const float* weight = (const float*)d_in[1];
    const float* scale  = (const float*)d_in[2];
    const float* bias   = (const float*)d_in[3];
    float* y = (float*)d_out;

    __hip_bfloat16* xq = (__hip_bfloat16*)d_ws;   // G*T*K bf16 = 117.4 MB

    // 1) act quant-dequant: G*T*KB = 458752 blocks of 128, 8 per 256-thread WG
    act_quant_kernel<<<(G_ * T_ * KB_) / 8, 256, 0, stream>>>(xs, xq);

    // 2) grouped GEMM: 8 groups * (8 x 16) tiles = 1024 WGs
    gemm_kernel<<<G_ * (T_ / 128) * (N_ / 128), 256, 0, stream>>>(
        xq, weight, scale, bias, y);
}

// Round 2
// 383.587 us; speedup vs baseline: 1.3667x; 1.3667x over previous
//
#include <hip/hip_runtime.h>
#include <hip/hip_bf16.h>
#include <stdint.h>

#define G_ 8
#define T_ 1024
#define K_ 7168
#define N_ 2048
#define KB_ (K_/128)   // 56
#define NB_ (N_/128)   // 16
#define NT_ (K_/64)    // 112 K-tiles

typedef __attribute__((ext_vector_type(4))) float f32x4;
typedef __attribute__((ext_vector_type(2))) float f32x2;
typedef __attribute__((ext_vector_type(8))) short bf16x8;

typedef __attribute__((address_space(3))) uint32_t lds_u32_t;
typedef const __attribute__((address_space(1))) uint32_t gbl_u32_t;

__device__ __forceinline__ void gload_lds16(const void* gsrc, const void* ldst)
{
    __builtin_amdgcn_global_load_lds(
        (gbl_u32_t*)(uintptr_t)gsrc,
        (lds_u32_t*)(uint32_t)(uintptr_t)ldst, 16, 0, 0);
}

__device__ __forceinline__ void blockbar()
{
    asm volatile("" ::: "memory");
    __builtin_amdgcn_s_barrier();
    asm volatile("" ::: "memory");
}

// ---------------------------------------------------------------------------
// Kernel 1: activation quantize->dequantize -> bf16 (per (token,128) amax/448)
// ---------------------------------------------------------------------------
__global__ __launch_bounds__(256) void act_quant_kernel(
    const float* __restrict__ xs, __hip_bfloat16* __restrict__ xq)
{
    const int grp = (blockIdx.x * 256 + threadIdx.x) >> 5;
    const int l   = threadIdx.x & 31;
    const size_t base = (size_t)grp * 128 + (size_t)l * 4;

    const float4 v = *(const float4*)(xs + base);
    float am = fmaxf(fmaxf(fabsf(v.x), fabsf(v.y)), fmaxf(fabsf(v.z), fabsf(v.w)));
#pragma unroll
    for (int off = 1; off <= 16; off <<= 1)
        am = fmaxf(am, __shfl_xor(am, off, 64));
    const float s = am / 448.0f;

    const int pk01 = __builtin_amdgcn_cvt_pk_fp8_f32(v.x / s, v.y / s, 0, false);
    const int pk23 = __builtin_amdgcn_cvt_pk_fp8_f32(v.z / s, v.w / s, 0, false);
    const f32x2 d01 = __builtin_amdgcn_cvt_pk_f32_fp8(pk01, false);
    const f32x2 d23 = __builtin_amdgcn_cvt_pk_f32_fp8(pk23, false);

    union { uint2 u; __hip_bfloat16 h[4]; } p;
    p.h[0] = __float2bfloat16(d01[0] * s);
    p.h[1] = __float2bfloat16(d01[1] * s);
    p.h[2] = __float2bfloat16(d23[0] * s);
    p.h[3] = __float2bfloat16(d23[1] * s);
    *(uint2*)(xq + base) = p.u;
}

// ---------------------------------------------------------------------------
// Kernel 2: weight dequant prepass: fp8-codes-in-fp32 * block scale -> bf16
// ---------------------------------------------------------------------------
__global__ __launch_bounds__(256) void wdeq_kernel(
    const float* __restrict__ w, const float* __restrict__ scale,
    __hip_bfloat16* __restrict__ wq)
{
    const size_t i8 = ((size_t)blockIdx.x * 256 + threadIdx.x) * 8;
    const int k   = (int)(i8 % K_);
    const int row = (int)(i8 / K_);         // g*N + n
    const int g   = row >> 11;              // N = 2048
    const int n   = row & (N_ - 1);
    const float s = scale[((size_t)g * NB_ + (n >> 7)) * KB_ + (k >> 7)];
    const float4 a = *(const float4*)(w + i8);
    const float4 b = *(const float4*)(w + i8 + 4);
    union { uint4 u; __hip_bfloat16 h[8]; } p;
    p.h[0] = __float2bfloat16(a.x * s);
    p.h[1] = __float2bfloat16(a.y * s);
    p.h[2] = __float2bfloat16(a.z * s);
    p.h[3] = __float2bfloat16(a.w * s);
    p.h[4] = __float2bfloat16(b.x * s);
    p.h[5] = __float2bfloat16(b.y * s);
    p.h[6] = __float2bfloat16(b.z * s);
    p.h[7] = __float2bfloat16(b.w * s);
    *(uint4*)(wq + i8) = p.u;
}

// ---------------------------------------------------------------------------
// Kernel 3: 256x256-tile 8-wave 4-phase pipelined bf16 GEMM (y = x W^T + b)
//   LDS 128 KiB: As[2][256][64], Bs[2][256][64] bf16, XOR-swizzled 16B slots.
//   Prefetch distance: 1 full K-tile staged across phases 2-4; vmcnt(8).
// ---------------------------------------------------------------------------
#define MFMA_Q(MH, NH)                                                        \
  { _Pragma("unroll") for (int m = 0; m < 4; ++m) {                           \
      _Pragma("unroll") for (int n = 0; n < 2; ++n) {                         \
        _Pragma("unroll") for (int ks = 0; ks < 2; ++ks) {                    \
          acc[(MH)*4+m][(NH)*2+n] = __builtin_amdgcn_mfma_f32_16x16x32_bf16(  \
              bA[m*2+ks], bB[((NH)*2+n)*2+ks], acc[(MH)*4+m][(NH)*2+n],       \
              0, 0, 0);                                                       \
  } } } }

#define LDA(m, ks, MH, b)                                                     \
  bA[(m)*2+(ks)] = *(const bf16x8*)(smem + (b)*32768 +                        \
      (wrow + (MH)*64 + (m)*16 + l15)*128 + colK[ks])

#define LDB(n, ks, b)                                                         \
  bB[(n)*2+(ks)] = *(const bf16x8*)(smem + 65536 + (b)*32768 +                \
      (wcol + (n)*16 + l15)*128 + colK[ks])

#define STG_A(c, t, b) gload_lds16(pA[c] + (size_t)(t)*64,                    \
      smem + (b)*32768 + (c)*8192 + dstw)
#define STG_B(c, t, b) gload_lds16(pB[c] + (size_t)(t)*64,                    \
      smem + 65536 + (b)*32768 + (c)*8192 + dstw)

__global__ __launch_bounds__(512) void gemm8_kernel(
    const __hip_bfloat16* __restrict__ xq, const __hip_bfloat16* __restrict__ wq,
    const float* __restrict__ bias, float* __restrict__ y)
{
    __shared__ char smem[131072];

    const int bx0 = blockIdx.x;
    const int bx  = (bx0 & 7) * 32 + (bx0 >> 3);   // XCD swizzle (256 % 8 == 0)
    const int g   = bx >> 5;
    const int tm  = (bx >> 3) & 3;
    const int tn  = bx & 7;
    const int t0  = tm * 256, n0 = tn * 256;

    const int tid = threadIdx.x, lane = tid & 63, wid = tid >> 6;
    const int l15 = lane & 15, lhi = lane >> 4;
    const int wrow = (wid >> 2) * 128;
    const int wcol = (wid & 3) * 64;

    const __hip_bfloat16* Ag = xq + (size_t)g * T_ * K_;
    const __hip_bfloat16* Bg = wq + (size_t)g * N_ * K_;

    // staging: lane writes LDS (row = c*64 + tid/8, slot = tid%8); source is
    // pre-swizzled so LDS(row,slot) holds global (row, slot ^ (row&7)).
    const int srow = tid >> 3;
    const int xoff = ((tid & 7) ^ (srow & 7)) * 8;
    const __hip_bfloat16* pA[4];
    const __hip_bfloat16* pB[4];
#pragma unroll
    for (int c = 0; c < 4; ++c) {
        pA[c] = Ag + (size_t)(t0 + c * 64 + srow) * K_ + xoff;
        pB[c] = Bg + (size_t)(n0 + c * 64 + srow) * K_ + xoff;
    }
    const int dstw = wid * 1024;

    // frag-read byte-column offsets with matching XOR swizzle
    const int rxor = (l15 & 7) << 4;
    int colK[2];
    colK[0] = (lhi * 16) ^ rxor;
    colK[1] = (64 + lhi * 16) ^ rxor;

    f32x4 acc[8][4] = {};
    bf16x8 bA[8], bB[8];

    // prologue: stage tile 0 -> buf0, tile 1 -> buf1 (16 loads/wave)
#pragma unroll
    for (int c = 0; c < 4; ++c) STG_A(c, 0, 0);
#pragma unroll
    for (int c = 0; c < 4; ++c) STG_B(c, 0, 0);
#pragma unroll
    for (int c = 0; c < 4; ++c) STG_A(c, 1, 1);
#pragma unroll
    for (int c = 0; c < 4; ++c) STG_B(c, 1, 1);
    asm volatile("s_waitcnt vmcnt(8)" ::: "memory");   // tile0 landed
    blockbar();

    for (int u = 0; u < NT_; ++u) {
        const int cb = u & 1;
        const bool pf = (u + 2 < NT_);

        // ---- ph1: read A rows {0-63,128-191} + B n0,n1 ----
        LDA(0,0,0,cb); LDA(0,1,0,cb); LDA(1,0,0,cb); LDA(1,1,0,cb);
        LDA(2,0,0,cb); LDA(2,1,0,cb); LDA(3,0,0,cb); LDA(3,1,0,cb);
        LDB(0,0,cb);   LDB(0,1,cb);   LDB(1,0,cb);   LDB(1,1,cb);
        blockbar();
        asm volatile("s_waitcnt lgkmcnt(0)" ::: "memory");
        __builtin_amdgcn_s_setprio(1);
        MFMA_Q(0, 0);
        __builtin_amdgcn_s_setprio(0);
        blockbar();

        // ---- ph2: read B n2,n3; stage A-even(u+2) (rows 0-63,128-191 free) --
        LDB(2,0,cb); LDB(2,1,cb); LDB(3,0,cb); LDB(3,1,cb);
        if (pf) { STG_A(0, u+2, cb); STG_A(2, u+2, cb); }
        blockbar();
        asm volatile("s_waitcnt lgkmcnt(0)" ::: "memory");
        __builtin_amdgcn_s_setprio(1);
        MFMA_Q(0, 1);
        __builtin_amdgcn_s_setprio(0);
        blockbar();

        // ---- ph3: read A rows {64-127,192-255}; stage B rows 0-127 (free) --
        LDA(0,0,1,cb); LDA(0,1,1,cb); LDA(1,0,1,cb); LDA(1,1,1,cb);
        LDA(2,0,1,cb); LDA(2,1,1,cb); LDA(3,0,1,cb); LDA(3,1,1,cb);
        if (pf) { STG_B(0, u+2, cb); STG_B(1, u+2, cb); }
        blockbar();
        asm volatile("s_waitcnt lgkmcnt(0)" ::: "memory");
        __builtin_amdgcn_s_setprio(1);
        MFMA_Q(1, 0);
        __builtin_amdgcn_s_setprio(0);
        blockbar();

        // ---- ph4: stage B rows 128-255 + A-odd(u+2); compute Q11 ----
        if (pf) { STG_B(2, u+2, cb); STG_B(3, u+2, cb);
                  STG_A(1, u+2, cb); STG_A(3, u+2, cb); }
        blockbar();
        __builtin_amdgcn_s_setprio(1);
        MFMA_Q(1, 1);
        __builtin_amdgcn_s_setprio(0);
        if (pf)                 asm volatile("s_waitcnt vmcnt(8)" ::: "memory");
        else if (u + 1 < NT_)   asm volatile("s_waitcnt vmcnt(0)" ::: "memory");
        blockbar();
    }

    // ---- epilogue: C/D layout col = lane&15, row = (lane>>4)*4 + j ----
    float* Yg = y + (size_t)g * T_ * N_;
#pragma unroll
    for (int n = 0; n < 4; ++n) {
        const int col = n0 + wcol + n * 16 + l15;
        const float bv = bias[g * N_ + col];
#pragma unroll
        for (int m = 0; m < 8; ++m) {
            const int r0 = t0 + wrow + m * 16 + lhi * 4;
#pragma unroll
            for (int j = 0; j < 4; ++j)
                Yg[(size_t)(r0 + j) * N_ + col] = acc[m][n][j] + bv;
        }
    }
}

// ---------------------------------------------------------------------------
// Fallback (round-1 verified): fused-dequant 128x128 GEMM, if ws too small
// ---------------------------------------------------------------------------
__global__ __launch_bounds__(256) void gemm_kernel(
    const __hip_bfloat16* __restrict__ xq, const float* __restrict__ w,
    const float* __restrict__ scale, const float* __restrict__ bias,
    float* __restrict__ y)
{
    __shared__ __hip_bfloat16 As[128][64];
    __shared__ __hip_bfloat16 Bs[128][64];

    const int bx = blockIdx.x;
    const int g  = bx >> 7;
    const int tm = (bx >> 4) & 7;
    const int tn = bx & 15;
    const int t0 = tm * 128;
    const int n0 = tn * 128;

    const int tid  = threadIdx.x;
    const int lane = tid & 63;
    const int wid  = tid >> 6;

    const __hip_bfloat16* Ag = xq + (size_t)g * T_ * K_;
    const float*          Wg = w  + (size_t)g * N_ * K_;

    const int arow = tid >> 3;
    const int acol = (tid & 7) * 8;
    const int brow0 = tid >> 4;
    const int bcol  = (tid & 15) * 4;

    const int wr  = (wid >> 1) * 64;
    const int wc  = (wid & 1) * 64;
    const int l15 = lane & 15;
    const int lhi = lane >> 4;

    f32x4 acc[4][4] = {};

    for (int kt = 0; kt < K_ / 64; ++kt) {
        const int k0 = kt * 64;
#pragma unroll
        for (int j = 0; j < 4; ++j) {
            const __hip_bfloat16* src =
                Ag + (size_t)(t0 + j * 32 + arow) * K_ + k0 + acol;
            gload_lds16(src, (char*)(&As[0][0]) + j * 4096 + wid * 1024);
        }
        const float svw = scale[((size_t)g * NB_ + tn) * KB_ + (kt >> 1)];
#pragma unroll
        for (int i = 0; i < 8; ++i) {
            const int r = i * 16 + brow0;
            const float4 wv = *(const float4*)(Wg + (size_t)(n0 + r) * K_ + k0 + bcol);
            union { uint2 u; __hip_bfloat16 h[4]; } p;
            p.h[0] = __float2bfloat16(wv.x * svw);
            p.h[1] = __float2bfloat16(wv.y * svw);
            p.h[2] = __float2bfloat16(wv.z * svw);
            p.h[3] = __float2bfloat16(wv.w * svw);
            *(uint2*)(&Bs[r][bcol]) = p.u;
        }
        __syncthreads();
#pragma unroll
        for (int kk = 0; kk < 64; kk += 32) {
            bf16x8 av[4], bv[4];
#pragma unroll
            for (int m = 0; m < 4; ++m)
                av[m] = *(const bf16x8*)&As[wr + m * 16 + l15][kk + lhi * 8];
#pragma unroll
            for (int n = 0; n < 4; ++n)
                bv[n] = *(const bf16x8*)&Bs[wc + n * 16 + l15][kk + lhi * 8];
#pragma unroll
            for (int m = 0; m < 4; ++m)
#pragma unroll
                for (int n = 0; n < 4; ++n)
                    acc[m][n] = __builtin_amdgcn_mfma_f32_16x16x32_bf16(
                        av[m], bv[n], acc[m][n], 0, 0, 0);
        }
        __syncthreads();
    }

    float* Yg = y + (size_t)g * T_ * N_;
#pragma unroll
    for (int n = 0; n < 4; ++n) {
        const int col = n0 + wc + n * 16 + l15;
        const float bv = bias[g * N_ + col];
#pragma unroll
        for (int m = 0; m < 4; ++m) {
            const int row0 = t0 + wr + m * 16 + lhi * 4;
#pragma unroll
            for (int j = 0; j < 4; ++j)
                Yg[(size_t)(row0 + j) * N_ + col] = acc[m][n][j] + bv;
        }
    }
}

// ---------------------------------------------------------------------------
extern "C" void kernel_launch(void* const* d_in, const int* in_sizes, int n_in,
                              void* d_out, int out_size, void* d_ws, size_t ws_size,
                              hipStream_t stream)
{
    const float* xs     = (const float*)d_in[0];
    const float* weight = (const float*)d_in[1];
    const float* scale  = (const float*)d_in[2];
    const float* bias   = (const float*)d_in[3];
    float* y = (float*)d_out;

    __hip_bfloat16* xq = (__hip_bfloat16*)d_ws;        // G*T*K bf16 = 117.4 MB
    const size_t xq_bytes = (size_t)G_ * T_ * K_ * 2;
    const size_t wq_bytes = (size_t)G_ * N_ * K_ * 2;  // 234.9 MB

    act_quant_kernel<<<(G_ * T_ * KB_) / 8, 256, 0, stream>>>(xs, xq);

    if (ws_size >= xq_bytes + wq_bytes) {
        __hip_bfloat16* wq = (__hip_bfloat16*)((char*)d_ws + xq_bytes);
        wdeq_kernel<<<(int)(((size_t)G_ * N_ * K_ / 8) / 256), 256, 0, stream>>>(
            weight, scale, wq);
        gemm8_kernel<<<256, 512, 0, stream>>>(xq, wq, bias, y);
    } else {
        gemm_kernel<<<G_ * (T_ / 128) * (N_ / 128), 256, 0, stream>>>(
            xq, weight, scale, bias, y);
    }
}